// Round 1
// baseline (3453.204 us; speedup 1.0000x reference)
//
#include <hip/hip_runtime.h>

// ---------------------------------------------------------------------------
// GraphSAGE 3-layer: per layer
//   agg[dst] += h[src]; cnt[dst] += 1            (atomic scatter)
//   mean = agg / max(cnt,1)
//   h' = act(mean @ Wn + h[:M] @ Ws + b)
// mean@Wn is computed as (agg@Wn)*inv_cnt[row]  (row-scalar factored out).
// ---------------------------------------------------------------------------

constexpr int D = 256;  // feature dim / K for all GEMMs

// One wave (64 lanes) per edge: float4/lane covers the full 256-float row.
__global__ __launch_bounds__(256) void scatter_mean_accum(
    const float* __restrict__ h, const int* __restrict__ src,
    const int* __restrict__ dst, float* __restrict__ agg,
    float* __restrict__ cnt, int E)
{
    int gid  = blockIdx.x * blockDim.x + threadIdx.x;
    int edge = gid >> 6;
    int lane = gid & 63;
    if (edge >= E) return;
    int s = src[edge];
    int d = dst[edge];
    float4 v = reinterpret_cast<const float4*>(h + (size_t)s * D)[lane];
    float* ap = agg + (size_t)d * D + lane * 4;
    atomicAdd(ap + 0, v.x);
    atomicAdd(ap + 1, v.y);
    atomicAdd(ap + 2, v.z);
    atomicAdd(ap + 3, v.w);
    if (lane == 0) atomicAdd(cnt + d, 1.0f);
}

__global__ __launch_bounds__(256) void make_inv(
    const float* __restrict__ cnt, float* __restrict__ inv, int M)
{
    int i = blockIdx.x * 256 + threadIdx.x;
    if (i < M) inv[i] = 1.0f / fmaxf(cnt[i], 1.0f);
}

// Dual GEMM: out = act(acc1*inv[row] + acc2 + b), acc1=agg@Wn, acc2=hsrc@Ws.
// 64x64 block tile, BK=16, 256 threads, 4x4 micro-tile per thread.
template <int RELU>
__global__ __launch_bounds__(256) void sage_linear(
    const float* __restrict__ agg, const float* __restrict__ inv,
    const float* __restrict__ hsrc,
    const float* __restrict__ Wn, const float* __restrict__ Ws,
    const float* __restrict__ bias, float* __restrict__ out,
    int M, int N)
{
    constexpr int BM = 64, BN = 64, BK = 16;
    constexpr int PA = BM + 4;  // pad: A-tile store would be 4-way conflicted at 64
    __shared__ float sA1[BK][PA];
    __shared__ float sA2[BK][PA];
    __shared__ float sB1[BK][BN];
    __shared__ float sB2[BK][BN];

    const int tid = threadIdx.x;
    const int bm = blockIdx.y * BM;
    const int bn = blockIdx.x * BN;
    const int tr = tid >> 4;          // 0..15  (row group)
    const int tc = tid & 15;          // 0..15  (col group)

    // A-tile load map: thread -> float4 at A[bm + tid/4][k0 + (tid%4)*4]
    const int ar = tid >> 2;          // 0..63
    const int ak = (tid & 3) * 4;     // 0,4,8,12
    // B-tile load map: thread -> float4 at W[k0 + tid/16][bn + (tid%16)*4]
    const int bk = tid >> 4;          // 0..15
    const int bc = (tid & 15) * 4;

    float acc1[4][4] = {};
    float acc2[4][4] = {};

    const int arow = bm + ar;
    const bool arow_ok = (arow < M);
    const float* aggp = agg  + (size_t)arow * D;
    const float* selp = hsrc + (size_t)arow * D;

    for (int k0 = 0; k0 < D; k0 += BK) {
        float4 va1 = arow_ok ? *(const float4*)(aggp + k0 + ak) : float4{0, 0, 0, 0};
        float4 va2 = arow_ok ? *(const float4*)(selp + k0 + ak) : float4{0, 0, 0, 0};
        float4 vb1 = *(const float4*)(Wn + (size_t)(k0 + bk) * N + bn + bc);
        float4 vb2 = *(const float4*)(Ws + (size_t)(k0 + bk) * N + bn + bc);
        __syncthreads();  // previous iteration's compute must finish before overwrite
        sA1[ak + 0][ar] = va1.x; sA1[ak + 1][ar] = va1.y;
        sA1[ak + 2][ar] = va1.z; sA1[ak + 3][ar] = va1.w;
        sA2[ak + 0][ar] = va2.x; sA2[ak + 1][ar] = va2.y;
        sA2[ak + 2][ar] = va2.z; sA2[ak + 3][ar] = va2.w;
        *(float4*)&sB1[bk][bc] = vb1;
        *(float4*)&sB2[bk][bc] = vb2;
        __syncthreads();
#pragma unroll
        for (int kk = 0; kk < BK; ++kk) {
            float4 a1 = *(const float4*)&sA1[kk][tr * 4];
            float4 a2 = *(const float4*)&sA2[kk][tr * 4];
            float4 b1 = *(const float4*)&sB1[kk][tc * 4];
            float4 b2 = *(const float4*)&sB2[kk][tc * 4];
            float a1v[4] = {a1.x, a1.y, a1.z, a1.w};
            float a2v[4] = {a2.x, a2.y, a2.z, a2.w};
            float b1v[4] = {b1.x, b1.y, b1.z, b1.w};
            float b2v[4] = {b2.x, b2.y, b2.z, b2.w};
#pragma unroll
            for (int i = 0; i < 4; ++i)
#pragma unroll
                for (int j = 0; j < 4; ++j) {
                    acc1[i][j] = fmaf(a1v[i], b1v[j], acc1[i][j]);
                    acc2[i][j] = fmaf(a2v[i], b2v[j], acc2[i][j]);
                }
        }
    }

#pragma unroll
    for (int i = 0; i < 4; ++i) {
        int row = bm + tr * 4 + i;
        if (row >= M) continue;
        float iv = inv[row];
        float4 o;
        float vals[4];
#pragma unroll
        for (int j = 0; j < 4; ++j) {
            int col = bn + tc * 4 + j;
            float v = acc1[i][j] * iv + acc2[i][j] + bias[col];
            if (RELU) v = fmaxf(v, 0.0f);
            vals[j] = v;
        }
        o.x = vals[0]; o.y = vals[1]; o.z = vals[2]; o.w = vals[3];
        *(float4*)(out + (size_t)row * N + bn + tc * 4) = o;
    }
}

extern "C" void kernel_launch(void* const* d_in, const int* in_sizes, int n_in,
                              void* d_out, int out_size, void* d_ws, size_t ws_size,
                              hipStream_t stream)
{
    const float* x   = (const float*)d_in[0];
    const float* Wn0 = (const float*)d_in[1];
    const float* Ws0 = (const float*)d_in[2];
    const float* b0  = (const float*)d_in[3];
    const float* Wn1 = (const float*)d_in[4];
    const float* Ws1 = (const float*)d_in[5];
    const float* b1  = (const float*)d_in[6];
    const float* Wn2 = (const float*)d_in[7];
    const float* Ws2 = (const float*)d_in[8];
    const float* b2  = (const float*)d_in[9];
    const int* src0 = (const int*)d_in[10];
    const int* dst0 = (const int*)d_in[11];
    const int* src1 = (const int*)d_in[12];
    const int* dst1 = (const int*)d_in[13];
    const int* src2 = (const int*)d_in[14];
    const int* dst2 = (const int*)d_in[15];
    const int E0 = in_sizes[10], E1 = in_sizes[12], E2 = in_sizes[14];
    const int M0 = 50000, M1 = 25000, M2 = 12500;

    // workspace layout (floats): agg(12.8M) | cnt(50k) | inv(50k) | h0(12.8M) | h1(6.4M)
    float* agg  = (float*)d_ws;
    float* cnt  = agg + (size_t)M0 * D;
    float* inv  = cnt + M0;
    float* h0   = inv + M0;
    float* h1   = h0 + (size_t)M0 * D;
    float* outp = (float*)d_out;

    auto run_layer = [&](const float* hin, const int* src, const int* dsti,
                         int E, int M, const float* Wn, const float* Ws,
                         const float* b, float* hout, int N, bool relu) {
        hipMemsetAsync(agg, 0, (size_t)M * D * sizeof(float), stream);
        hipMemsetAsync(cnt, 0, (size_t)M * sizeof(float), stream);
        scatter_mean_accum<<<dim3((E + 3) / 4), dim3(256), 0, stream>>>(
            hin, src, dsti, agg, cnt, E);
        make_inv<<<dim3((M + 255) / 256), dim3(256), 0, stream>>>(cnt, inv, M);
        dim3 ggrd(N / 64, (M + 63) / 64);
        if (relu)
            sage_linear<1><<<ggrd, dim3(256), 0, stream>>>(agg, inv, hin, Wn, Ws, b, hout, M, N);
        else
            sage_linear<0><<<ggrd, dim3(256), 0, stream>>>(agg, inv, hin, Wn, Ws, b, hout, M, N);
    };

    run_layer(x,  src0, dst0, E0, M0, Wn0, Ws0, b0, h0,   256, true);
    run_layer(h0, src1, dst1, E1, M1, Wn1, Ws1, b1, h1,   256, true);
    run_layer(h1, src2, dst2, E2, M2, Wn2, Ws2, b2, outp, 128, false);
}

// Round 2
// 742.476 us; speedup vs baseline: 4.6509x; 4.6509x over previous
//
#include <hip/hip_runtime.h>

// ---------------------------------------------------------------------------
// GraphSAGE 3-layer. Per layer:
//   CSR build (hist -> scan -> scatter)  [no float atomics]
//   mean[d] = (1/deg) * sum_{e: dst=d} h[src[e]]      (gather, 1 wave/node)
//   h' = act(mean @ Wn + h[:M] @ Ws + b)               (dual fp32 GEMM)
// ---------------------------------------------------------------------------

constexpr int D = 256;  // feature dim / K for all GEMMs

// ---- CSR build ------------------------------------------------------------

__global__ __launch_bounds__(256) void hist_kernel(
    const int* __restrict__ dst, int* __restrict__ cnt, int E)
{
    int i = blockIdx.x * 256 + threadIdx.x;
    if (i < E) atomicAdd(&cnt[dst[i]], 1);
}

// Per block: exclusive-scan a 2048-element chunk; emit block total.
__global__ __launch_bounds__(256) void scan_partial(
    const int* __restrict__ cnt, int* __restrict__ rowptr,
    int* __restrict__ bsums, int M)
{
    __shared__ int lds[256];
    const int base = blockIdx.x * 2048;
    const int t = threadIdx.x;
    int v[8];
    int s = 0;
#pragma unroll
    for (int j = 0; j < 8; ++j) {
        int idx = base + t * 8 + j;
        v[j] = s;
        int c = (idx < M) ? cnt[idx] : 0;
        s += c;
    }
    lds[t] = s;
    __syncthreads();
    for (int off = 1; off < 256; off <<= 1) {
        int x = (t >= off) ? lds[t - off] : 0;
        __syncthreads();
        lds[t] += x;
        __syncthreads();
    }
    int texcl = (t == 0) ? 0 : lds[t - 1];
    if (t == 255) bsums[blockIdx.x] = lds[255];
#pragma unroll
    for (int j = 0; j < 8; ++j) {
        int idx = base + t * 8 + j;
        if (idx < M) rowptr[idx] = texcl + v[j];
    }
}

// Serial exclusive scan of block sums (nb <= 32, trivial).
__global__ void scan_bsums(int* bsums, int nb)
{
    if (blockIdx.x == 0 && threadIdx.x == 0) {
        int s = 0;
        for (int i = 0; i < nb; ++i) { int c = bsums[i]; bsums[i] = s; s += c; }
    }
}

__global__ __launch_bounds__(256) void scan_add(
    int* __restrict__ rowptr, int* __restrict__ wptr,
    const int* __restrict__ bsums, int M, int E)
{
    int i = blockIdx.x * 256 + threadIdx.x;
    if (i < M) {
        int r = rowptr[i] + bsums[i >> 11];
        rowptr[i] = r;
        wptr[i] = r;
    }
    if (i == 0) rowptr[M] = E;
}

__global__ __launch_bounds__(256) void scatter_csr(
    const int* __restrict__ src, const int* __restrict__ dst,
    int* __restrict__ wptr, int* __restrict__ csr_src, int E)
{
    int i = blockIdx.x * 256 + threadIdx.x;
    if (i < E) {
        int p = atomicAdd(&wptr[dst[i]], 1);
        csr_src[p] = src[i];
    }
}

// ---- Aggregation: one wave per dst node, row accumulated in registers -----

__global__ __launch_bounds__(256) void aggregate_mean(
    const float* __restrict__ h, const int* __restrict__ rowptr,
    const int* __restrict__ csr_src, float* __restrict__ mean, int M)
{
    int gid = blockIdx.x * 256 + threadIdx.x;
    int node = gid >> 6;
    int lane = gid & 63;
    if (node >= M) return;
    int beg = rowptr[node];
    int end = rowptr[node + 1];
    float4 acc{0.f, 0.f, 0.f, 0.f};
    int e = beg;
    // Full groups of 8: lanes 0..7 fetch 8 indices, broadcast via shfl so the
    // 8 row loads are independent (MLP) within the unrolled body.
    for (; e + 8 <= end; e += 8) {
        int sidx = csr_src[e + (lane & 7)];
#pragma unroll
        for (int j = 0; j < 8; ++j) {
            int s = __shfl(sidx, j);
            float4 v = reinterpret_cast<const float4*>(h + (size_t)s * D)[lane];
            acc.x += v.x; acc.y += v.y; acc.z += v.z; acc.w += v.w;
        }
    }
    for (; e < end; ++e) {
        int s = csr_src[e];
        float4 v = reinterpret_cast<const float4*>(h + (size_t)s * D)[lane];
        acc.x += v.x; acc.y += v.y; acc.z += v.z; acc.w += v.w;
    }
    float invd = 1.0f / (float)max(end - beg, 1);
    acc.x *= invd; acc.y *= invd; acc.z *= invd; acc.w *= invd;
    reinterpret_cast<float4*>(mean + (size_t)node * D)[lane] = acc;
}

// ---- Dual GEMM: out = act(mean@Wn + hsrc@Ws + b) --------------------------
// 64x64 block tile, BK=16, 256 threads, 4x4 micro-tile per thread.

template <int RELU>
__global__ __launch_bounds__(256) void sage_linear(
    const float* __restrict__ mean, const float* __restrict__ hsrc,
    const float* __restrict__ Wn, const float* __restrict__ Ws,
    const float* __restrict__ bias, float* __restrict__ out,
    int M, int N)
{
    constexpr int BM = 64, BN = 64, BK = 16;
    constexpr int PA = BM + 4;  // pad: A-tile store would be 4-way conflicted at 64
    __shared__ float sA1[BK][PA];
    __shared__ float sA2[BK][PA];
    __shared__ float sB1[BK][BN];
    __shared__ float sB2[BK][BN];

    const int tid = threadIdx.x;
    const int bm = blockIdx.y * BM;
    const int bn = blockIdx.x * BN;
    const int tr = tid >> 4;          // 0..15  (row group)
    const int tc = tid & 15;          // 0..15  (col group)

    const int ar = tid >> 2;          // 0..63
    const int ak = (tid & 3) * 4;     // 0,4,8,12
    const int bk = tid >> 4;          // 0..15
    const int bc = (tid & 15) * 4;

    float acc1[4][4] = {};
    float acc2[4][4] = {};

    const int arow = bm + ar;
    const bool arow_ok = (arow < M);
    const float* mp = mean + (size_t)arow * D;
    const float* sp = hsrc + (size_t)arow * D;

    for (int k0 = 0; k0 < D; k0 += BK) {
        float4 va1 = arow_ok ? *(const float4*)(mp + k0 + ak) : float4{0, 0, 0, 0};
        float4 va2 = arow_ok ? *(const float4*)(sp + k0 + ak) : float4{0, 0, 0, 0};
        float4 vb1 = *(const float4*)(Wn + (size_t)(k0 + bk) * N + bn + bc);
        float4 vb2 = *(const float4*)(Ws + (size_t)(k0 + bk) * N + bn + bc);
        __syncthreads();
        sA1[ak + 0][ar] = va1.x; sA1[ak + 1][ar] = va1.y;
        sA1[ak + 2][ar] = va1.z; sA1[ak + 3][ar] = va1.w;
        sA2[ak + 0][ar] = va2.x; sA2[ak + 1][ar] = va2.y;
        sA2[ak + 2][ar] = va2.z; sA2[ak + 3][ar] = va2.w;
        *(float4*)&sB1[bk][bc] = vb1;
        *(float4*)&sB2[bk][bc] = vb2;
        __syncthreads();
#pragma unroll
        for (int kk = 0; kk < BK; ++kk) {
            float4 a1 = *(const float4*)&sA1[kk][tr * 4];
            float4 a2 = *(const float4*)&sA2[kk][tr * 4];
            float4 b1 = *(const float4*)&sB1[kk][tc * 4];
            float4 b2 = *(const float4*)&sB2[kk][tc * 4];
            float a1v[4] = {a1.x, a1.y, a1.z, a1.w};
            float a2v[4] = {a2.x, a2.y, a2.z, a2.w};
            float b1v[4] = {b1.x, b1.y, b1.z, b1.w};
            float b2v[4] = {b2.x, b2.y, b2.z, b2.w};
#pragma unroll
            for (int i = 0; i < 4; ++i)
#pragma unroll
                for (int j = 0; j < 4; ++j) {
                    acc1[i][j] = fmaf(a1v[i], b1v[j], acc1[i][j]);
                    acc2[i][j] = fmaf(a2v[i], b2v[j], acc2[i][j]);
                }
        }
    }

#pragma unroll
    for (int i = 0; i < 4; ++i) {
        int row = bm + tr * 4 + i;
        if (row >= M) continue;
        float vals[4];
#pragma unroll
        for (int j = 0; j < 4; ++j) {
            int col = bn + tc * 4 + j;
            float v = acc1[i][j] + acc2[i][j] + bias[col];
            if (RELU) v = fmaxf(v, 0.0f);
            vals[j] = v;
        }
        float4 o{vals[0], vals[1], vals[2], vals[3]};
        *(float4*)(out + (size_t)row * N + bn + tc * 4) = o;
    }
}

// ---------------------------------------------------------------------------

extern "C" void kernel_launch(void* const* d_in, const int* in_sizes, int n_in,
                              void* d_out, int out_size, void* d_ws, size_t ws_size,
                              hipStream_t stream)
{
    const float* x   = (const float*)d_in[0];
    const float* Wn0 = (const float*)d_in[1];
    const float* Ws0 = (const float*)d_in[2];
    const float* b0  = (const float*)d_in[3];
    const float* Wn1 = (const float*)d_in[4];
    const float* Ws1 = (const float*)d_in[5];
    const float* b1  = (const float*)d_in[6];
    const float* Wn2 = (const float*)d_in[7];
    const float* Ws2 = (const float*)d_in[8];
    const float* b2  = (const float*)d_in[9];
    const int* src0 = (const int*)d_in[10];
    const int* dst0 = (const int*)d_in[11];
    const int* src1 = (const int*)d_in[12];
    const int* dst1 = (const int*)d_in[13];
    const int* src2 = (const int*)d_in[14];
    const int* dst2 = (const int*)d_in[15];
    const int E0 = in_sizes[10], E1 = in_sizes[12], E2 = in_sizes[14];
    const int M0 = 50000, M1 = 25000, M2 = 12500;

    // workspace layout (floats / ints):
    // mean: M0*D f | h0: M0*D f | h1: M1*D f | cnt/wptr: M0 i | rowptr: M0+1 i
    // bsums: 64 i | csr_src: E0 i
    float* mean = (float*)d_ws;
    float* h0   = mean + (size_t)M0 * D;
    float* h1   = h0 + (size_t)M0 * D;
    int* cnt    = (int*)(h1 + (size_t)M1 * D);
    int* rowptr = cnt + M0;
    int* bsums  = rowptr + M0 + 1;
    int* csr    = bsums + 64;
    float* outp = (float*)d_out;

    auto run_layer = [&](const float* hin, const int* src, const int* dsti,
                         int E, int M, const float* Wn, const float* Ws,
                         const float* b, float* hout, int N, bool relu) {
        hipMemsetAsync(cnt, 0, (size_t)M * sizeof(int), stream);
        hist_kernel<<<dim3((E + 255) / 256), dim3(256), 0, stream>>>(dsti, cnt, E);
        int nb = (M + 2047) / 2048;
        scan_partial<<<dim3(nb), dim3(256), 0, stream>>>(cnt, rowptr, bsums, M);
        scan_bsums<<<dim3(1), dim3(64), 0, stream>>>(bsums, nb);
        scan_add<<<dim3((M + 255) / 256), dim3(256), 0, stream>>>(rowptr, cnt, bsums, M, E);
        scatter_csr<<<dim3((E + 255) / 256), dim3(256), 0, stream>>>(src, dsti, cnt, csr, E);
        aggregate_mean<<<dim3((M * 64 + 255) / 256), dim3(256), 0, stream>>>(
            hin, rowptr, csr, mean, M);
        dim3 ggrd(N / 64, (M + 63) / 64);
        if (relu)
            sage_linear<1><<<ggrd, dim3(256), 0, stream>>>(mean, hin, Wn, Ws, b, hout, M, N);
        else
            sage_linear<0><<<ggrd, dim3(256), 0, stream>>>(mean, hin, Wn, Ws, b, hout, M, N);
    };

    run_layer(x,  src0, dst0, E0, M0, Wn0, Ws0, b0, h0,   256, true);
    run_layer(h0, src1, dst1, E1, M1, Wn1, Ws1, b1, h1,   256, true);
    run_layer(h1, src2, dst2, E2, M2, Wn2, Ws2, b2, outp, 128, false);
}

// Round 4
// 484.646 us; speedup vs baseline: 7.1252x; 1.5320x over previous
//
#include <hip/hip_runtime.h>
#include <hip/hip_bf16.h>

// ---------------------------------------------------------------------------
// GraphSAGE 3-layer, bf16 datapath:
//   x -> bf16 once; weights -> Wt[N][512] bf16 (K-major, Wn||Ws) once.
//   Per layer: CSR build -> gather-mean (bf16 in, fp32 accum, bf16 out)
//              -> fused-K MFMA GEMM  C = [mean|h] @ Wt^T  (+bias, ReLU)
//   Layers 0/1 emit bf16 h; layer 2 emits fp32 to d_out.
// R4 fixes vs R3: (1) LDS staging now covers the FULL 64-wide K tile
// (4x float4 per thread, was 2x -> half the tile was uninitialized -> NaN);
// (2) h1 sized 25088 rows (layer-1 output is 25000 rows; R3 alloc'd 12544
// and clobbered the weight/CSR scratch).
// ---------------------------------------------------------------------------

typedef __attribute__((ext_vector_type(8))) short bf16x8;   // 8 bf16 = 4 VGPR
typedef __attribute__((ext_vector_type(4))) float floatx4;

__device__ inline unsigned short f2bf(float f) {
    union { float f; unsigned int u; } v{f};
    unsigned int u = v.u;
    return (unsigned short)((u + 0x7FFFu + ((u >> 16) & 1u)) >> 16);  // RNE
}
__device__ inline float bf2f(unsigned short h) {
    union { unsigned int u; float f; } v{(unsigned int)h << 16};
    return v.f;
}

// ---- one-time conversions -------------------------------------------------

__global__ __launch_bounds__(256) void cast_bf16(
    const float* __restrict__ in, unsigned short* __restrict__ out, long n4)
{
    long i = (long)blockIdx.x * 256 + threadIdx.x;
    if (i >= n4) return;
    float4 v = reinterpret_cast<const float4*>(in)[i];
    ushort4 o{f2bf(v.x), f2bf(v.y), f2bf(v.z), f2bf(v.w)};
    reinterpret_cast<ushort4*>(out)[i] = o;
}

// Wt[n][k] = Wn[k][n]; Wt[n][256+k] = Ws[k][n].  (K=256 fixed)
__global__ __launch_bounds__(256) void prep_w(
    const float* __restrict__ Wn, const float* __restrict__ Ws,
    unsigned short* __restrict__ Wt, int N)
{
    int idx = blockIdx.x * 256 + threadIdx.x;     // over N*256, k fastest
    int n = idx >> 8, k = idx & 255;
    if (n >= N) return;
    Wt[(size_t)n * 512 + k]       = f2bf(Wn[(size_t)k * N + n]);
    Wt[(size_t)n * 512 + 256 + k] = f2bf(Ws[(size_t)k * N + n]);
}

// ---- CSR build ------------------------------------------------------------

__global__ __launch_bounds__(256) void hist_kernel(
    const int* __restrict__ dst, int* __restrict__ cnt, int E)
{
    int i = blockIdx.x * 256 + threadIdx.x;
    if (i < E) atomicAdd(&cnt[dst[i]], 1);
}

__global__ __launch_bounds__(256) void scan_partial(
    const int* __restrict__ cnt, int* __restrict__ rowptr,
    int* __restrict__ bsums, int M)
{
    __shared__ int lds[256];
    const int base = blockIdx.x * 2048;
    const int t = threadIdx.x;
    int v[8];
    int s = 0;
#pragma unroll
    for (int j = 0; j < 8; ++j) {
        int idx = base + t * 8 + j;
        v[j] = s;
        int c = (idx < M) ? cnt[idx] : 0;
        s += c;
    }
    lds[t] = s;
    __syncthreads();
    for (int off = 1; off < 256; off <<= 1) {
        int x = (t >= off) ? lds[t - off] : 0;
        __syncthreads();
        lds[t] += x;
        __syncthreads();
    }
    int texcl = (t == 0) ? 0 : lds[t - 1];
    if (t == 255) bsums[blockIdx.x] = lds[255];
#pragma unroll
    for (int j = 0; j < 8; ++j) {
        int idx = base + t * 8 + j;
        if (idx < M) rowptr[idx] = texcl + v[j];
    }
}

__global__ void scan_bsums(int* bsums, int nb)
{
    if (blockIdx.x == 0 && threadIdx.x == 0) {
        int s = 0;
        for (int i = 0; i < nb; ++i) { int c = bsums[i]; bsums[i] = s; s += c; }
    }
}

__global__ __launch_bounds__(256) void scan_add(
    int* __restrict__ rowptr, int* __restrict__ wptr,
    const int* __restrict__ bsums, int M, int E)
{
    int i = blockIdx.x * 256 + threadIdx.x;
    if (i < M) {
        int r = rowptr[i] + bsums[i >> 11];
        rowptr[i] = r;
        wptr[i] = r;
    }
    if (i == 0) rowptr[M] = E;
}

__global__ __launch_bounds__(256) void scatter_csr(
    const int* __restrict__ src, const int* __restrict__ dst,
    int* __restrict__ wptr, int* __restrict__ csr_src, int E)
{
    int i = blockIdx.x * 256 + threadIdx.x;
    if (i < E) {
        int p = atomicAdd(&wptr[dst[i]], 1);
        csr_src[p] = src[i];
    }
}

// ---- Aggregation: 1 wave/node, bf16 rows (512B), fp32 accum ---------------

__global__ __launch_bounds__(256) void aggregate_mean_bf16(
    const unsigned short* __restrict__ h, const int* __restrict__ rowptr,
    const int* __restrict__ csr_src, unsigned short* __restrict__ mean, int M)
{
    int gid = blockIdx.x * 256 + threadIdx.x;
    int node = gid >> 6;
    int lane = gid & 63;
    if (node >= M) return;
    int beg = rowptr[node];
    int end = rowptr[node + 1];
    float ax = 0.f, ay = 0.f, az = 0.f, aw = 0.f;
    int e = beg;
    for (; e + 8 <= end; e += 8) {
        int sidx = csr_src[e + (lane & 7)];
#pragma unroll
        for (int j = 0; j < 8; ++j) {
            int s = __shfl(sidx, j);
            ushort4 v = *(const ushort4*)(h + (size_t)s * 256 + lane * 4);
            ax += bf2f(v.x); ay += bf2f(v.y); az += bf2f(v.z); aw += bf2f(v.w);
        }
    }
    for (; e < end; ++e) {
        int s = csr_src[e];
        ushort4 v = *(const ushort4*)(h + (size_t)s * 256 + lane * 4);
        ax += bf2f(v.x); ay += bf2f(v.y); az += bf2f(v.z); aw += bf2f(v.w);
    }
    float invd = 1.0f / (float)max(end - beg, 1);
    ushort4 o{f2bf(ax * invd), f2bf(ay * invd), f2bf(az * invd), f2bf(aw * invd)};
    *(ushort4*)(mean + (size_t)node * 256 + lane * 4) = o;
}

// ---- Fused-K MFMA GEMM ----------------------------------------------------
// C[m][n] = sum_{k<512} Acat[m][k] * Wt[n][k],  Acat = [mean | h] (K-concat).
// 128x128 block tile, BK=64, 4 waves, 64x64/wave as 4x4 mfma_f32_16x16x32_bf16.
// A1/A2 must be readable up to ceil128(M) rows (allocations padded).

template <int RELU, int OUT_BF16>
__global__ __launch_bounds__(256) void sage_mfma(
    const unsigned short* __restrict__ A1,  // mean  [>=ceil128(M)][256]
    const unsigned short* __restrict__ A2,  // hsrc  [>=ceil128(M)][256]
    const unsigned short* __restrict__ Wt,  // [N][512]
    const float* __restrict__ bias,
    void* __restrict__ out, int M, int N)
{
    constexpr int PK = 64 + 8;  // LDS row pitch in bf16 (144 B)
    __shared__ unsigned short sA[128][PK];
    __shared__ unsigned short sB[128][PK];

    const int tid = threadIdx.x;
    const int bm = blockIdx.y * 128;
    const int bn = blockIdx.x * 128;
    const int wid = tid >> 6, lane = tid & 63;
    const int wm = (wid >> 1) * 64;       // wave row offset
    const int wn = (wid & 1) * 64;        // wave col offset
    const int quad = lane >> 4, l16 = lane & 15;

    // staging map: thread t -> row t>>1 (0..127), 32-bf16 half (t&1)
    const int sr = tid >> 1;
    const int sc = (tid & 1) * 32;        // bf16 units; covers sc..sc+31

    floatx4 acc[4][4] = {};

    for (int k0 = 0; k0 < 512; k0 += 64) {
        const unsigned short* Ab = (k0 < 256) ? A1 : A2;
        const int ak = k0 & 255;
        const float4* ag = (const float4*)(Ab + (size_t)(bm + sr) * 256 + ak + sc);
        float4 a0 = ag[0], a1 = ag[1], a2 = ag[2], a3 = ag[3];
        const float4* bg = (const float4*)(Wt + (size_t)(bn + sr) * 512 + k0 + sc);
        float4 b0 = bg[0], b1 = bg[1], b2 = bg[2], b3 = bg[3];
        __syncthreads();  // prior compute must finish before overwrite
        *(float4*)&sA[sr][sc]      = a0;
        *(float4*)&sA[sr][sc + 8]  = a1;
        *(float4*)&sA[sr][sc + 16] = a2;
        *(float4*)&sA[sr][sc + 24] = a3;
        *(float4*)&sB[sr][sc]      = b0;
        *(float4*)&sB[sr][sc + 8]  = b1;
        *(float4*)&sB[sr][sc + 16] = b2;
        *(float4*)&sB[sr][sc + 24] = b3;
        __syncthreads();
#pragma unroll
        for (int ks = 0; ks < 64; ks += 32) {
            bf16x8 af[4], bfr[4];
#pragma unroll
            for (int i = 0; i < 4; ++i)
                af[i] = *(const bf16x8*)&sA[wm + i * 16 + l16][ks + quad * 8];
#pragma unroll
            for (int j = 0; j < 4; ++j)
                bfr[j] = *(const bf16x8*)&sB[wn + j * 16 + l16][ks + quad * 8];
#pragma unroll
            for (int i = 0; i < 4; ++i)
#pragma unroll
                for (int j = 0; j < 4; ++j)
                    acc[i][j] = __builtin_amdgcn_mfma_f32_16x16x32_bf16(
                        af[i], bfr[j], acc[i][j], 0, 0, 0);
        }
    }

    // epilogue: C row = quad*4 + reg, col = l16 (verified m89/m91)
#pragma unroll
    for (int j = 0; j < 4; ++j) {
        int col = bn + wn + j * 16 + l16;
        float bcol = bias[col];
#pragma unroll
        for (int i = 0; i < 4; ++i) {
#pragma unroll
            for (int r = 0; r < 4; ++r) {
                int row = bm + wm + i * 16 + quad * 4 + r;
                if (row < M) {
                    float v = acc[i][j][r] + bcol;
                    if (RELU) v = fmaxf(v, 0.0f);
                    if (OUT_BF16)
                        ((unsigned short*)out)[(size_t)row * N + col] = f2bf(v);
                    else
                        ((float*)out)[(size_t)row * N + col] = v;
                }
            }
        }
    }
}

// ---------------------------------------------------------------------------

extern "C" void kernel_launch(void* const* d_in, const int* in_sizes, int n_in,
                              void* d_out, int out_size, void* d_ws, size_t ws_size,
                              hipStream_t stream)
{
    const float* x   = (const float*)d_in[0];
    const float* Wn0 = (const float*)d_in[1];
    const float* Ws0 = (const float*)d_in[2];
    const float* b0  = (const float*)d_in[3];
    const float* Wn1 = (const float*)d_in[4];
    const float* Ws1 = (const float*)d_in[5];
    const float* b1  = (const float*)d_in[6];
    const float* Wn2 = (const float*)d_in[7];
    const float* Ws2 = (const float*)d_in[8];
    const float* b2  = (const float*)d_in[9];
    const int* src0 = (const int*)d_in[10];
    const int* dst0 = (const int*)d_in[11];
    const int* src1 = (const int*)d_in[12];
    const int* dst1 = (const int*)d_in[13];
    const int* src2 = (const int*)d_in[14];
    const int* dst2 = (const int*)d_in[15];
    const int E0 = in_sizes[10], E1 = in_sizes[12], E2 = in_sizes[14];
    const int M0 = 50000, M1 = 25000, M2 = 12500;
    const int NSRC = 100000;

    // --- workspace layout (bf16 = unsigned short) ---
    // Row padding: mean ceil128(M0)=50048; h1 needs 25088 (layer-1 output is
    // 25000 rows AND layer-2 GEMM reads up to row 12543 / gather up to 24999).
    unsigned short* xb   = (unsigned short*)d_ws;             // [100000][256]
    unsigned short* mean = xb   + (size_t)NSRC  * 256;        // [50048][256]
    unsigned short* h0   = mean + (size_t)50048 * 256;        // [50000][256]
    unsigned short* h1   = h0   + (size_t)50000 * 256;        // [25088][256]
    unsigned short* Wt0  = h1   + (size_t)25088 * 256;        // [256][512]
    unsigned short* Wt1  = Wt0  + 256 * 512;
    unsigned short* Wt2  = Wt1  + 256 * 512;                  // [128][512]
    int* cnt    = (int*)(Wt2 + 128 * 512);
    int* rowptr = cnt + M0;
    int* bsums  = rowptr + M0 + 1;
    int* csr    = bsums + 64;
    float* outp = (float*)d_out;

    // conversions (rerun every call for graph safety)
    cast_bf16<<<dim3((NSRC * 256 / 4 + 255) / 256), dim3(256), 0, stream>>>(
        x, xb, (long)NSRC * 64);
    prep_w<<<dim3(256), dim3(256), 0, stream>>>(Wn0, Ws0, Wt0, 256);
    prep_w<<<dim3(256), dim3(256), 0, stream>>>(Wn1, Ws1, Wt1, 256);
    prep_w<<<dim3(128), dim3(256), 0, stream>>>(Wn2, Ws2, Wt2, 128);

    auto run_layer = [&](const unsigned short* hin, const int* src, const int* dsti,
                         int E, int M, const unsigned short* Wt, const float* b,
                         void* hout, int N, bool relu, bool out_bf16) {
        hipMemsetAsync(cnt, 0, (size_t)M * sizeof(int), stream);
        hist_kernel<<<dim3((E + 255) / 256), dim3(256), 0, stream>>>(dsti, cnt, E);
        int nb = (M + 2047) / 2048;
        scan_partial<<<dim3(nb), dim3(256), 0, stream>>>(cnt, rowptr, bsums, M);
        scan_bsums<<<dim3(1), dim3(64), 0, stream>>>(bsums, nb);
        scan_add<<<dim3((M + 255) / 256), dim3(256), 0, stream>>>(rowptr, cnt, bsums, M, E);
        scatter_csr<<<dim3((E + 255) / 256), dim3(256), 0, stream>>>(src, dsti, cnt, csr, E);
        aggregate_mean_bf16<<<dim3((M * 64 + 255) / 256), dim3(256), 0, stream>>>(
            hin, rowptr, csr, mean, M);
        dim3 g(N / 128, (M + 127) / 128);
        if (out_bf16)
            sage_mfma<1, 1><<<g, dim3(256), 0, stream>>>(mean, hin, Wt, b, hout, M, N);
        else
            sage_mfma<0, 0><<<g, dim3(256), 0, stream>>>(mean, hin, Wt, b, hout, M, N);
    };

    run_layer(xb, src0, dst0, E0, M0, Wt0, b0, h0,   256, true,  true);
    run_layer(h0, src1, dst1, E1, M1, Wt1, b1, h1,   256, true,  true);
    run_layer(h1, src2, dst2, E2, M2, Wt2, b2, outp, 128, false, false);
}

// Round 5
// 454.263 us; speedup vs baseline: 7.6018x; 1.0669x over previous
//
#include <hip/hip_runtime.h>
#include <hip/hip_bf16.h>

// ---------------------------------------------------------------------------
// GraphSAGE 3-layer, bf16 datapath, batched CSR build.
//   - CSR for ALL 3 layers built in one pass (edge lists are inputs; no
//     dependence on h). Concatenated node space: L0 [0,50000),
//     L1 [50000,75000), L2 [75000,87500). Global exclusive scan gives
//     per-layer edge offsets automatically (boundaries at E0, E0+E1).
//   - Per layer: gather-mean (bf16 in, fp32 accum) -> fused-K MFMA GEMM
//     C = [mean|h] @ Wt^T (+bias, ReLU). Layers 0/1 emit bf16; layer 2 fp32.
//   - 13 dispatches total (was 31 in R4; the serial small-kernel chain was
//     costing ~300 us of launch/drain overhead).
// ---------------------------------------------------------------------------

typedef __attribute__((ext_vector_type(8))) short bf16x8;   // 8 bf16 = 4 VGPR
typedef __attribute__((ext_vector_type(4))) float floatx4;

constexpr int M0 = 50000, M1 = 25000, M2 = 12500;
constexpr int NODE_OFF1 = 50000, NODE_OFF2 = 75000, M_TOT = 87500;

__device__ inline unsigned short f2bf(float f) {
    union { float f; unsigned int u; } v{f};
    unsigned int u = v.u;
    return (unsigned short)((u + 0x7FFFu + ((u >> 16) & 1u)) >> 16);  // RNE
}
__device__ inline float bf2f(unsigned short h) {
    union { unsigned int u; float f; } v{(unsigned int)h << 16};
    return v.f;
}

// ---- one-time conversions -------------------------------------------------

__global__ __launch_bounds__(256) void cast_bf16(
    const float* __restrict__ in, unsigned short* __restrict__ out, long n4)
{
    long i = (long)blockIdx.x * 256 + threadIdx.x;
    if (i >= n4) return;
    float4 v = reinterpret_cast<const float4*>(in)[i];
    ushort4 o{f2bf(v.x), f2bf(v.y), f2bf(v.z), f2bf(v.w)};
    reinterpret_cast<ushort4*>(out)[i] = o;
}

// All 3 weight pairs -> Wt[n][512] bf16 (K-major, Wn||Ws), one dispatch.
// Block ranges: [0,256) -> layer0 (N=256), [256,512) -> layer1 (N=256),
// [512,640) -> layer2 (N=128).
__global__ __launch_bounds__(256) void prep_w_all(
    const float* __restrict__ Wn0, const float* __restrict__ Ws0,
    const float* __restrict__ Wn1, const float* __restrict__ Ws1,
    const float* __restrict__ Wn2, const float* __restrict__ Ws2,
    unsigned short* __restrict__ Wt0, unsigned short* __restrict__ Wt1,
    unsigned short* __restrict__ Wt2)
{
    int blk = blockIdx.x;
    const float* Wn; const float* Ws; unsigned short* Wt; int N; int base;
    if (blk < 256)      { Wn = Wn0; Ws = Ws0; Wt = Wt0; N = 256; base = 0; }
    else if (blk < 512) { Wn = Wn1; Ws = Ws1; Wt = Wt1; N = 256; base = 256; }
    else                { Wn = Wn2; Ws = Ws2; Wt = Wt2; N = 128; base = 512; }
    int idx = (blk - base) * 256 + threadIdx.x;   // over N*256, k fastest
    int n = idx >> 8, k = idx & 255;
    if (n >= N) return;
    Wt[(size_t)n * 512 + k]       = f2bf(Wn[(size_t)k * N + n]);
    Wt[(size_t)n * 512 + 256 + k] = f2bf(Ws[(size_t)k * N + n]);
}

// ---- batched CSR build ----------------------------------------------------

__global__ __launch_bounds__(256) void hist_all(
    const int* __restrict__ dst0, const int* __restrict__ dst1,
    const int* __restrict__ dst2, int* __restrict__ cnt,
    int E0, int E1, int E2)
{
    int i = blockIdx.x * 256 + threadIdx.x;
    if (i < E0) {
        atomicAdd(&cnt[dst0[i]], 1);
    } else if (i < E0 + E1) {
        atomicAdd(&cnt[NODE_OFF1 + dst1[i - E0]], 1);
    } else if (i < E0 + E1 + E2) {
        atomicAdd(&cnt[NODE_OFF2 + dst2[i - E0 - E1]], 1);
    }
}

// Per block: exclusive-scan a 2048-element chunk; emit block total.
__global__ __launch_bounds__(256) void scan_partial(
    const int* __restrict__ cnt, int* __restrict__ rowptr,
    int* __restrict__ bsums, int M)
{
    __shared__ int lds[256];
    const int base = blockIdx.x * 2048;
    const int t = threadIdx.x;
    int v[8];
    int s = 0;
#pragma unroll
    for (int j = 0; j < 8; ++j) {
        int idx = base + t * 8 + j;
        v[j] = s;
        int c = (idx < M) ? cnt[idx] : 0;
        s += c;
    }
    lds[t] = s;
    __syncthreads();
    for (int off = 1; off < 256; off <<= 1) {
        int x = (t >= off) ? lds[t - off] : 0;
        __syncthreads();
        lds[t] += x;
        __syncthreads();
    }
    int texcl = (t == 0) ? 0 : lds[t - 1];
    if (t == 255) bsums[blockIdx.x] = lds[255];
#pragma unroll
    for (int j = 0; j < 8; ++j) {
        int idx = base + t * 8 + j;
        if (idx < M) rowptr[idx] = texcl + v[j];
    }
}

// Adds the bsums prefix (computed inline: i>>11 is constant per 256-block).
__global__ __launch_bounds__(256) void scan_add(
    int* __restrict__ rowptr, int* __restrict__ wptr,
    const int* __restrict__ bsums, int M, int E_tot)
{
    __shared__ int sprefix;
    const int chunk = blockIdx.x >> 3;   // 2048-chunk index for this block
    if (threadIdx.x == 0) {
        int s = 0;
        for (int j = 0; j < chunk; ++j) s += bsums[j];
        sprefix = s;
    }
    __syncthreads();
    int i = blockIdx.x * 256 + threadIdx.x;
    if (i < M) {
        int r = rowptr[i] + sprefix;
        rowptr[i] = r;
        wptr[i] = r;
    }
    if (i == 0) rowptr[M] = E_tot;
}

__global__ __launch_bounds__(256) void scatter_all(
    const int* __restrict__ src0, const int* __restrict__ dst0,
    const int* __restrict__ src1, const int* __restrict__ dst1,
    const int* __restrict__ src2, const int* __restrict__ dst2,
    int* __restrict__ wptr, int* __restrict__ csr,
    int E0, int E1, int E2)
{
    int i = blockIdx.x * 256 + threadIdx.x;
    int node, s;
    if (i < E0) {
        node = dst0[i]; s = src0[i];
    } else if (i < E0 + E1) {
        int j = i - E0; node = NODE_OFF1 + dst1[j]; s = src1[j];
    } else if (i < E0 + E1 + E2) {
        int j = i - E0 - E1; node = NODE_OFF2 + dst2[j]; s = src2[j];
    } else return;
    int p = atomicAdd(&wptr[node], 1);
    csr[p] = s;
}

// ---- Aggregation: 1 wave/node, bf16 rows (512B), fp32 accum ---------------

__global__ __launch_bounds__(256) void aggregate_mean_bf16(
    const unsigned short* __restrict__ h, const int* __restrict__ rowptr,
    const int* __restrict__ csr_src, unsigned short* __restrict__ mean, int M)
{
    int gid = blockIdx.x * 256 + threadIdx.x;
    int node = gid >> 6;
    int lane = gid & 63;
    if (node >= M) return;
    int beg = rowptr[node];
    int end = rowptr[node + 1];
    float ax = 0.f, ay = 0.f, az = 0.f, aw = 0.f;
    int e = beg;
    for (; e + 8 <= end; e += 8) {
        int sidx = csr_src[e + (lane & 7)];
#pragma unroll
        for (int j = 0; j < 8; ++j) {
            int s = __shfl(sidx, j);
            ushort4 v = *(const ushort4*)(h + (size_t)s * 256 + lane * 4);
            ax += bf2f(v.x); ay += bf2f(v.y); az += bf2f(v.z); aw += bf2f(v.w);
        }
    }
    for (; e < end; ++e) {
        int s = csr_src[e];
        ushort4 v = *(const ushort4*)(h + (size_t)s * 256 + lane * 4);
        ax += bf2f(v.x); ay += bf2f(v.y); az += bf2f(v.z); aw += bf2f(v.w);
    }
    float invd = 1.0f / (float)max(end - beg, 1);
    ushort4 o{f2bf(ax * invd), f2bf(ay * invd), f2bf(az * invd), f2bf(aw * invd)};
    *(ushort4*)(mean + (size_t)node * 256 + lane * 4) = o;
}

// ---- Fused-K MFMA GEMM ----------------------------------------------------
// C[m][n] = sum_{k<512} Acat[m][k] * Wt[n][k],  Acat = [mean | h] (K-concat).
// 128x128 block tile, BK=64, 4 waves, 64x64/wave as 4x4 mfma_f32_16x16x32_bf16.

template <int RELU, int OUT_BF16>
__global__ __launch_bounds__(256) void sage_mfma(
    const unsigned short* __restrict__ A1,  // mean  [>=ceil128(M)][256]
    const unsigned short* __restrict__ A2,  // hsrc  [>=ceil128(M)][256]
    const unsigned short* __restrict__ Wt,  // [N][512]
    const float* __restrict__ bias,
    void* __restrict__ out, int M, int N)
{
    constexpr int PK = 64 + 8;  // LDS row pitch in bf16 (144 B)
    __shared__ unsigned short sA[128][PK];
    __shared__ unsigned short sB[128][PK];

    const int tid = threadIdx.x;
    const int bm = blockIdx.y * 128;
    const int bn = blockIdx.x * 128;
    const int wid = tid >> 6, lane = tid & 63;
    const int wm = (wid >> 1) * 64;
    const int wn = (wid & 1) * 64;
    const int quad = lane >> 4, l16 = lane & 15;

    // staging map: thread t -> row t>>1 (0..127), 32-bf16 half (t&1)
    const int sr = tid >> 1;
    const int sc = (tid & 1) * 32;

    floatx4 acc[4][4] = {};

    for (int k0 = 0; k0 < 512; k0 += 64) {
        const unsigned short* Ab = (k0 < 256) ? A1 : A2;
        const int ak = k0 & 255;
        const float4* ag = (const float4*)(Ab + (size_t)(bm + sr) * 256 + ak + sc);
        float4 a0 = ag[0], a1 = ag[1], a2 = ag[2], a3 = ag[3];
        const float4* bg = (const float4*)(Wt + (size_t)(bn + sr) * 512 + k0 + sc);
        float4 b0 = bg[0], b1 = bg[1], b2 = bg[2], b3 = bg[3];
        __syncthreads();
        *(float4*)&sA[sr][sc]      = a0;
        *(float4*)&sA[sr][sc + 8]  = a1;
        *(float4*)&sA[sr][sc + 16] = a2;
        *(float4*)&sA[sr][sc + 24] = a3;
        *(float4*)&sB[sr][sc]      = b0;
        *(float4*)&sB[sr][sc + 8]  = b1;
        *(float4*)&sB[sr][sc + 16] = b2;
        *(float4*)&sB[sr][sc + 24] = b3;
        __syncthreads();
#pragma unroll
        for (int ks = 0; ks < 64; ks += 32) {
            bf16x8 af[4], bfr[4];
#pragma unroll
            for (int i = 0; i < 4; ++i)
                af[i] = *(const bf16x8*)&sA[wm + i * 16 + l16][ks + quad * 8];
#pragma unroll
            for (int j = 0; j < 4; ++j)
                bfr[j] = *(const bf16x8*)&sB[wn + j * 16 + l16][ks + quad * 8];
#pragma unroll
            for (int i = 0; i < 4; ++i)
#pragma unroll
                for (int j = 0; j < 4; ++j)
                    acc[i][j] = __builtin_amdgcn_mfma_f32_16x16x32_bf16(
                        af[i], bfr[j], acc[i][j], 0, 0, 0);
        }
    }

    // epilogue: C row = quad*4 + reg, col = l16 (verified m89/m91)
#pragma unroll
    for (int j = 0; j < 4; ++j) {
        int col = bn + wn + j * 16 + l16;
        float bcol = bias[col];
#pragma unroll
        for (int i = 0; i < 4; ++i) {
#pragma unroll
            for (int r = 0; r < 4; ++r) {
                int row = bm + wm + i * 16 + quad * 4 + r;
                if (row < M) {
                    float v = acc[i][j][r] + bcol;
                    if (RELU) v = fmaxf(v, 0.0f);
                    if (OUT_BF16)
                        ((unsigned short*)out)[(size_t)row * N + col] = f2bf(v);
                    else
                        ((float*)out)[(size_t)row * N + col] = v;
                }
            }
        }
    }
}

// ---------------------------------------------------------------------------

extern "C" void kernel_launch(void* const* d_in, const int* in_sizes, int n_in,
                              void* d_out, int out_size, void* d_ws, size_t ws_size,
                              hipStream_t stream)
{
    const float* x   = (const float*)d_in[0];
    const float* Wn0 = (const float*)d_in[1];
    const float* Ws0 = (const float*)d_in[2];
    const float* b0  = (const float*)d_in[3];
    const float* Wn1 = (const float*)d_in[4];
    const float* Ws1 = (const float*)d_in[5];
    const float* b1  = (const float*)d_in[6];
    const float* Wn2 = (const float*)d_in[7];
    const float* Ws2 = (const float*)d_in[8];
    const float* b2  = (const float*)d_in[9];
    const int* src0 = (const int*)d_in[10];
    const int* dst0 = (const int*)d_in[11];
    const int* src1 = (const int*)d_in[12];
    const int* dst1 = (const int*)d_in[13];
    const int* src2 = (const int*)d_in[14];
    const int* dst2 = (const int*)d_in[15];
    const int E0 = in_sizes[10], E1 = in_sizes[12], E2 = in_sizes[14];
    const int E_tot = E0 + E1 + E2;
    const int NSRC = 100000;

    // --- workspace layout ---
    unsigned short* xb   = (unsigned short*)d_ws;             // [100000][256]
    unsigned short* mean = xb   + (size_t)NSRC  * 256;        // [50048][256]
    unsigned short* h0   = mean + (size_t)50048 * 256;        // [50048][256]
    unsigned short* h1   = h0   + (size_t)50048 * 256;        // [25088][256]
    unsigned short* Wt0  = h1   + (size_t)25088 * 256;        // [256][512]
    unsigned short* Wt1  = Wt0  + 256 * 512;
    unsigned short* Wt2  = Wt1  + 256 * 512;                  // [128][512]
    int* cnt    = (int*)(Wt2 + 128 * 512);                    // [87500]
    int* rowptr = cnt + M_TOT;                                // [87501]
    int* wptr   = rowptr + M_TOT + 1;                         // [87500]
    int* bsums  = wptr + M_TOT;                               // [64]
    int* csr    = bsums + 64;                                 // [E_tot]
    float* outp = (float*)d_out;

    // conversions (rerun every call for graph safety)
    cast_bf16<<<dim3((NSRC * 256 / 4 + 255) / 256), dim3(256), 0, stream>>>(
        x, xb, (long)NSRC * 64);
    prep_w_all<<<dim3(640), dim3(256), 0, stream>>>(
        Wn0, Ws0, Wn1, Ws1, Wn2, Ws2, Wt0, Wt1, Wt2);

    // batched CSR build for all 3 layers
    hipMemsetAsync(cnt, 0, (size_t)M_TOT * sizeof(int), stream);
    hist_all<<<dim3((E_tot + 255) / 256), dim3(256), 0, stream>>>(
        dst0, dst1, dst2, cnt, E0, E1, E2);
    int nb = (M_TOT + 2047) / 2048;
    scan_partial<<<dim3(nb), dim3(256), 0, stream>>>(cnt, rowptr, bsums, M_TOT);
    scan_add<<<dim3((M_TOT + 255) / 256), dim3(256), 0, stream>>>(
        rowptr, wptr, bsums, M_TOT, E_tot);
    scatter_all<<<dim3((E_tot + 255) / 256), dim3(256), 0, stream>>>(
        src0, dst0, src1, dst1, src2, dst2, wptr, csr, E0, E1, E2);

    auto run_layer = [&](const unsigned short* hin, int node_off, int M,
                         const unsigned short* Wt, const float* b,
                         void* hout, int N, bool relu, bool out_bf16) {
        aggregate_mean_bf16<<<dim3((M * 64 + 255) / 256), dim3(256), 0, stream>>>(
            hin, rowptr + node_off, csr, mean, M);
        dim3 g(N / 128, (M + 127) / 128);
        if (out_bf16)
            sage_mfma<1, 1><<<g, dim3(256), 0, stream>>>(mean, hin, Wt, b, hout, M, N);
        else
            sage_mfma<0, 0><<<g, dim3(256), 0, stream>>>(mean, hin, Wt, b, hout, M, N);
    };

    run_layer(xb, 0,         M0, Wt0, b0, h0,   256, true,  true);
    run_layer(h0, NODE_OFF1, M1, Wt1, b1, h1,   256, true,  true);
    run_layer(h1, NODE_OFF2, M2, Wt2, b2, outp, 128, false, false);
}

// Round 6
// 431.855 us; speedup vs baseline: 7.9962x; 1.0519x over previous
//
#include <hip/hip_runtime.h>
#include <hip/hip_bf16.h>

// ---------------------------------------------------------------------------
// GraphSAGE 3-layer, bf16 datapath, batched CSR build.
// R6 changes vs R5:
//   (1) scatter_all -> XCD-partitioned scatter: blockIdx&7 selects a node
//       partition (round-robin WG->XCD dispatch heuristic); each partition
//       writes a CONTIGUOUS csr range so L2 lines fill before eviction.
//       R5 counters: scatter WRITE_SIZE 49MB for a 3.5MB buffer (partial-line
//       cross-XCD evictions) at 61us. Predicted ~6MB / ~15-20us.
//   (2) cast_bf16 + prep_w_all + hist_all merged into one front_kernel
//       (independent work, block-range split) - 2 fewer dispatch boundaries.
// ---------------------------------------------------------------------------

typedef __attribute__((ext_vector_type(8))) short bf16x8;   // 8 bf16 = 4 VGPR
typedef __attribute__((ext_vector_type(4))) float floatx4;

constexpr int M0 = 50000, M1 = 25000, M2 = 12500;
constexpr int NODE_OFF1 = 50000, NODE_OFF2 = 75000, M_TOT = 87500;
constexpr int NSRC = 100000;
constexpr int NPART = 8;

__device__ inline unsigned short f2bf(float f) {
    union { float f; unsigned int u; } v{f};
    unsigned int u = v.u;
    return (unsigned short)((u + 0x7FFFu + ((u >> 16) & 1u)) >> 16);  // RNE
}
__device__ inline float bf2f(unsigned short h) {
    union { unsigned int u; float f; } v{(unsigned int)h << 16};
    return v.f;
}

// ---- fused front-end: x->bf16 cast | weight transpose | dst histogram -----
// block ranges: [0, CAST_B) cast, [CAST_B, CAST_B+640) prep, rest hist.
constexpr int CAST_B = 25000;           // NSRC*256/4 / 256
constexpr int PREP_B = 640;

__global__ __launch_bounds__(256) void front_kernel(
    const float* __restrict__ x, unsigned short* __restrict__ xb,
    const float* __restrict__ Wn0, const float* __restrict__ Ws0,
    const float* __restrict__ Wn1, const float* __restrict__ Ws1,
    const float* __restrict__ Wn2, const float* __restrict__ Ws2,
    unsigned short* __restrict__ Wt0, unsigned short* __restrict__ Wt1,
    unsigned short* __restrict__ Wt2,
    const int* __restrict__ dst0, const int* __restrict__ dst1,
    const int* __restrict__ dst2, int* __restrict__ cnt,
    int E0, int E1, int E2)
{
    const int blk = blockIdx.x;
    if (blk < CAST_B) {
        long i = (long)blk * 256 + threadIdx.x;     // over NSRC*64 ushort4's
        float4 v = reinterpret_cast<const float4*>(x)[i];
        ushort4 o{f2bf(v.x), f2bf(v.y), f2bf(v.z), f2bf(v.w)};
        reinterpret_cast<ushort4*>(xb)[i] = o;
    } else if (blk < CAST_B + PREP_B) {
        int b = blk - CAST_B;
        const float* Wn; const float* Ws; unsigned short* Wt; int N; int base;
        if (b < 256)      { Wn = Wn0; Ws = Ws0; Wt = Wt0; N = 256; base = 0; }
        else if (b < 512) { Wn = Wn1; Ws = Ws1; Wt = Wt1; N = 256; base = 256; }
        else              { Wn = Wn2; Ws = Ws2; Wt = Wt2; N = 128; base = 512; }
        int idx = (b - base) * 256 + threadIdx.x;   // over N*256, k fastest
        int n = idx >> 8, k = idx & 255;
        if (n >= N) return;
        Wt[(size_t)n * 512 + k]       = f2bf(Wn[(size_t)k * N + n]);
        Wt[(size_t)n * 512 + 256 + k] = f2bf(Ws[(size_t)k * N + n]);
    } else {
        int i = (blk - CAST_B - PREP_B) * 256 + threadIdx.x;
        if (i < E0) {
            atomicAdd(&cnt[dst0[i]], 1);
        } else if (i < E0 + E1) {
            atomicAdd(&cnt[NODE_OFF1 + dst1[i - E0]], 1);
        } else if (i < E0 + E1 + E2) {
            atomicAdd(&cnt[NODE_OFF2 + dst2[i - E0 - E1]], 1);
        }
    }
}

// ---- scan: per-2048-chunk exclusive scan + chunk totals -------------------

__global__ __launch_bounds__(256) void scan_partial(
    const int* __restrict__ cnt, int* __restrict__ rowptr,
    int* __restrict__ bsums, int M)
{
    __shared__ int lds[256];
    const int base = blockIdx.x * 2048;
    const int t = threadIdx.x;
    int v[8];
    int s = 0;
#pragma unroll
    for (int j = 0; j < 8; ++j) {
        int idx = base + t * 8 + j;
        v[j] = s;
        int c = (idx < M) ? cnt[idx] : 0;
        s += c;
    }
    lds[t] = s;
    __syncthreads();
    for (int off = 1; off < 256; off <<= 1) {
        int x = (t >= off) ? lds[t - off] : 0;
        __syncthreads();
        lds[t] += x;
        __syncthreads();
    }
    int texcl = (t == 0) ? 0 : lds[t - 1];
    if (t == 255) bsums[blockIdx.x] = lds[255];
#pragma unroll
    for (int j = 0; j < 8; ++j) {
        int idx = base + t * 8 + j;
        if (idx < M) rowptr[idx] = texcl + v[j];
    }
}

__global__ __launch_bounds__(256) void scan_add(
    int* __restrict__ rowptr, int* __restrict__ wptr,
    const int* __restrict__ bsums, int M, int E_tot)
{
    __shared__ int sprefix;
    const int chunk = blockIdx.x >> 3;   // 2048-chunk index for this block
    if (threadIdx.x == 0) {
        int s = 0;
        for (int j = 0; j < chunk; ++j) s += bsums[j];
        sprefix = s;
    }
    __syncthreads();
    int i = blockIdx.x * 256 + threadIdx.x;
    if (i < M) {
        int r = rowptr[i] + sprefix;
        rowptr[i] = r;
        wptr[i] = r;
    }
    if (i == 0) rowptr[M] = E_tot;
}

// ---- XCD-partitioned CSR scatter ------------------------------------------
// blockIdx&7 = node partition (contiguous node range -> contiguous csr range,
// since rowptr is monotone). blockIdx>>3 = edge slice. Each slice is read by
// all 8 partitions (8x read amp on 7MB of edge lists = cheap); each block
// commits only its partition's edges, so csr/wptr lines stay XCD-local.

__global__ __launch_bounds__(256) void scatter_part(
    const int* __restrict__ src0, const int* __restrict__ dst0,
    const int* __restrict__ src1, const int* __restrict__ dst1,
    const int* __restrict__ src2, const int* __restrict__ dst2,
    int* __restrict__ wptr, int* __restrict__ csr,
    int E0, int E1, int E2)
{
    const int part = blockIdx.x & (NPART - 1);
    const int i = (blockIdx.x >> 3) * 256 + threadIdx.x;
    const int lo = (int)(((long)M_TOT * part) / NPART);
    const int hi = (int)(((long)M_TOT * (part + 1)) / NPART);
    int node, s;
    if (i < E0) {
        node = dst0[i]; s = src0[i];
    } else if (i < E0 + E1) {
        int j = i - E0; node = NODE_OFF1 + dst1[j]; s = src1[j];
    } else if (i < E0 + E1 + E2) {
        int j = i - E0 - E1; node = NODE_OFF2 + dst2[j]; s = src2[j];
    } else return;
    if (node >= lo && node < hi) {
        int p = atomicAdd(&wptr[node], 1);
        csr[p] = s;
    }
}

// ---- Aggregation: 1 wave/node, bf16 rows (512B), fp32 accum ---------------

__global__ __launch_bounds__(256) void aggregate_mean_bf16(
    const unsigned short* __restrict__ h, const int* __restrict__ rowptr,
    const int* __restrict__ csr_src, unsigned short* __restrict__ mean, int M)
{
    int gid = blockIdx.x * 256 + threadIdx.x;
    int node = gid >> 6;
    int lane = gid & 63;
    if (node >= M) return;
    int beg = rowptr[node];
    int end = rowptr[node + 1];
    float ax = 0.f, ay = 0.f, az = 0.f, aw = 0.f;
    int e = beg;
    for (; e + 8 <= end; e += 8) {
        int sidx = csr_src[e + (lane & 7)];
#pragma unroll
        for (int j = 0; j < 8; ++j) {
            int s = __shfl(sidx, j);
            ushort4 v = *(const ushort4*)(h + (size_t)s * 256 + lane * 4);
            ax += bf2f(v.x); ay += bf2f(v.y); az += bf2f(v.z); aw += bf2f(v.w);
        }
    }
    for (; e < end; ++e) {
        int s = csr_src[e];
        ushort4 v = *(const ushort4*)(h + (size_t)s * 256 + lane * 4);
        ax += bf2f(v.x); ay += bf2f(v.y); az += bf2f(v.z); aw += bf2f(v.w);
    }
    float invd = 1.0f / (float)max(end - beg, 1);
    ushort4 o{f2bf(ax * invd), f2bf(ay * invd), f2bf(az * invd), f2bf(aw * invd)};
    *(ushort4*)(mean + (size_t)node * 256 + lane * 4) = o;
}

// ---- Fused-K MFMA GEMM ----------------------------------------------------
// C[m][n] = sum_{k<512} Acat[m][k] * Wt[n][k],  Acat = [mean | h] (K-concat).
// 128x128 block tile, BK=64, 4 waves, 64x64/wave as 4x4 mfma_f32_16x16x32_bf16.

template <int RELU, int OUT_BF16>
__global__ __launch_bounds__(256) void sage_mfma(
    const unsigned short* __restrict__ A1,  // mean  [>=ceil128(M)][256]
    const unsigned short* __restrict__ A2,  // hsrc  [>=ceil128(M)][256]
    const unsigned short* __restrict__ Wt,  // [N][512]
    const float* __restrict__ bias,
    void* __restrict__ out, int M, int N)
{
    constexpr int PK = 64 + 8;  // LDS row pitch in bf16 (144 B)
    __shared__ unsigned short sA[128][PK];
    __shared__ unsigned short sB[128][PK];

    const int tid = threadIdx.x;
    const int bm = blockIdx.y * 128;
    const int bn = blockIdx.x * 128;
    const int wid = tid >> 6, lane = tid & 63;
    const int wm = (wid >> 1) * 64;
    const int wn = (wid & 1) * 64;
    const int quad = lane >> 4, l16 = lane & 15;

    const int sr = tid >> 1;
    const int sc = (tid & 1) * 32;

    floatx4 acc[4][4] = {};

    for (int k0 = 0; k0 < 512; k0 += 64) {
        const unsigned short* Ab = (k0 < 256) ? A1 : A2;
        const int ak = k0 & 255;
        const float4* ag = (const float4*)(Ab + (size_t)(bm + sr) * 256 + ak + sc);
        float4 a0 = ag[0], a1 = ag[1], a2 = ag[2], a3 = ag[3];
        const float4* bg = (const float4*)(Wt + (size_t)(bn + sr) * 512 + k0 + sc);
        float4 b0 = bg[0], b1 = bg[1], b2 = bg[2], b3 = bg[3];
        __syncthreads();
        *(float4*)&sA[sr][sc]      = a0;
        *(float4*)&sA[sr][sc + 8]  = a1;
        *(float4*)&sA[sr][sc + 16] = a2;
        *(float4*)&sA[sr][sc + 24] = a3;
        *(float4*)&sB[sr][sc]      = b0;
        *(float4*)&sB[sr][sc + 8]  = b1;
        *(float4*)&sB[sr][sc + 16] = b2;
        *(float4*)&sB[sr][sc + 24] = b3;
        __syncthreads();
#pragma unroll
        for (int ks = 0; ks < 64; ks += 32) {
            bf16x8 af[4], bfr[4];
#pragma unroll
            for (int i = 0; i < 4; ++i)
                af[i] = *(const bf16x8*)&sA[wm + i * 16 + l16][ks + quad * 8];
#pragma unroll
            for (int j = 0; j < 4; ++j)
                bfr[j] = *(const bf16x8*)&sB[wn + j * 16 + l16][ks + quad * 8];
#pragma unroll
            for (int i = 0; i < 4; ++i)
#pragma unroll
                for (int j = 0; j < 4; ++j)
                    acc[i][j] = __builtin_amdgcn_mfma_f32_16x16x32_bf16(
                        af[i], bfr[j], acc[i][j], 0, 0, 0);
        }
    }

    // epilogue: C row = quad*4 + reg, col = l16 (verified m89/m91)
#pragma unroll
    for (int j = 0; j < 4; ++j) {
        int col = bn + wn + j * 16 + l16;
        float bcol = bias[col];
#pragma unroll
        for (int i = 0; i < 4; ++i) {
#pragma unroll
            for (int r = 0; r < 4; ++r) {
                int row = bm + wm + i * 16 + quad * 4 + r;
                if (row < M) {
                    float v = acc[i][j][r] + bcol;
                    if (RELU) v = fmaxf(v, 0.0f);
                    if (OUT_BF16)
                        ((unsigned short*)out)[(size_t)row * N + col] = f2bf(v);
                    else
                        ((float*)out)[(size_t)row * N + col] = v;
                }
            }
        }
    }
}

// ---------------------------------------------------------------------------

extern "C" void kernel_launch(void* const* d_in, const int* in_sizes, int n_in,
                              void* d_out, int out_size, void* d_ws, size_t ws_size,
                              hipStream_t stream)
{
    const float* x   = (const float*)d_in[0];
    const float* Wn0 = (const float*)d_in[1];
    const float* Ws0 = (const float*)d_in[2];
    const float* b0  = (const float*)d_in[3];
    const float* Wn1 = (const float*)d_in[4];
    const float* Ws1 = (const float*)d_in[5];
    const float* b1  = (const float*)d_in[6];
    const float* Wn2 = (const float*)d_in[7];
    const float* Ws2 = (const float*)d_in[8];
    const float* b2  = (const float*)d_in[9];
    const int* src0 = (const int*)d_in[10];
    const int* dst0 = (const int*)d_in[11];
    const int* src1 = (const int*)d_in[12];
    const int* dst1 = (const int*)d_in[13];
    const int* src2 = (const int*)d_in[14];
    const int* dst2 = (const int*)d_in[15];
    const int E0 = in_sizes[10], E1 = in_sizes[12], E2 = in_sizes[14];
    const int E_tot = E0 + E1 + E2;

    // --- workspace layout ---
    unsigned short* xb   = (unsigned short*)d_ws;             // [100000][256]
    unsigned short* mean = xb   + (size_t)NSRC  * 256;        // [50048][256]
    unsigned short* h0   = mean + (size_t)50048 * 256;        // [50048][256]
    unsigned short* h1   = h0   + (size_t)50048 * 256;        // [25088][256]
    unsigned short* Wt0  = h1   + (size_t)25088 * 256;        // [256][512]
    unsigned short* Wt1  = Wt0  + 256 * 512;
    unsigned short* Wt2  = Wt1  + 256 * 512;                  // [128][512]
    int* cnt    = (int*)(Wt2 + 128 * 512);                    // [87500]
    int* rowptr = cnt + M_TOT;                                // [87501]
    int* wptr   = rowptr + M_TOT + 1;                         // [87500]
    int* bsums  = wptr + M_TOT;                               // [64]
    int* csr    = bsums + 64;                                 // [E_tot]
    float* outp = (float*)d_out;

    // cnt must be zero before front_kernel's hist atomics (stream-ordered).
    hipMemsetAsync(cnt, 0, (size_t)M_TOT * sizeof(int), stream);

    const int hist_b = (E_tot + 255) / 256;
    front_kernel<<<dim3(CAST_B + PREP_B + hist_b), dim3(256), 0, stream>>>(
        x, xb, Wn0, Ws0, Wn1, Ws1, Wn2, Ws2, Wt0, Wt1, Wt2,
        dst0, dst1, dst2, cnt, E0, E1, E2);

    int nb = (M_TOT + 2047) / 2048;
    scan_partial<<<dim3(nb), dim3(256), 0, stream>>>(cnt, rowptr, bsums, M_TOT);
    scan_add<<<dim3((M_TOT + 255) / 256), dim3(256), 0, stream>>>(
        rowptr, wptr, bsums, M_TOT, E_tot);
    scatter_part<<<dim3(NPART * hist_b), dim3(256), 0, stream>>>(
        src0, dst0, src1, dst1, src2, dst2, wptr, csr, E0, E1, E2);

    auto run_layer = [&](const unsigned short* hin, int node_off, int M,
                         const unsigned short* Wt, const float* b,
                         void* hout, int N, bool relu, bool out_bf16) {
        aggregate_mean_bf16<<<dim3((M * 64 + 255) / 256), dim3(256), 0, stream>>>(
            hin, rowptr + node_off, csr, mean, M);
        dim3 g(N / 128, (M + 127) / 128);
        if (out_bf16)
            sage_mfma<1, 1><<<g, dim3(256), 0, stream>>>(mean, hin, Wt, b, hout, M, N);
        else
            sage_mfma<0, 0><<<g, dim3(256), 0, stream>>>(mean, hin, Wt, b, hout, M, N);
    };

    run_layer(xb, 0,         M0, Wt0, b0, h0,   256, true,  true);
    run_layer(h0, NODE_OFF1, M1, Wt1, b1, h1,   256, true,  true);
    run_layer(h1, NODE_OFF2, M2, Wt2, b2, outp, 128, false, false);
}